// Round 19
// baseline (239.436 us; speedup 1.0000x reference)
//
#include <hip/hip_runtime.h>
#include <math.h>

#define LTOK 2304
#define CDIM 768
#define NHEAD 12
#define HDIM 64
#define HS 48

typedef short s16x8 __attribute__((ext_vector_type(8)));   // 8 bf16 bits (4 VGPRs)
typedef float f32x4 __attribute__((ext_vector_type(4)));

__device__ __forceinline__ unsigned short f2b(float f) {
  __bf16 b = (__bf16)f;   // RNE
  return __builtin_bit_cast(unsigned short, b);
}
__device__ __forceinline__ float b2f(unsigned short u) {
  unsigned int x = ((unsigned int)u) << 16;
  return __builtin_bit_cast(float, x);
}

__device__ __forceinline__ void gld_lds16(void* lds, const void* g) {
  __builtin_amdgcn_global_load_lds(
      (const __attribute__((address_space(1))) unsigned int*)g,
      (__attribute__((address_space(3))) unsigned int*)lds, 16, 0, 0);
}

// ---- fused: fp32->bf16 of all 4 weight tensors + RoPE cos/sin table ----
// vec8 segments: wq 221184 | wproj 73728 | wfc1 294912 | wfc2 294912 = 884736
// then 73728 rope-table entries. grid = (884736 + 73728) / 256 = 3744.
__global__ __launch_bounds__(256) void f2b5_kernel(const float* __restrict__ a0,
                                                   const float* __restrict__ a1,
                                                   const float* __restrict__ a2,
                                                   const float* __restrict__ a3,
                                                   unsigned short* __restrict__ d0,
                                                   unsigned short* __restrict__ d1,
                                                   unsigned short* __restrict__ d2,
                                                   unsigned short* __restrict__ d3,
                                                   float* __restrict__ cs,
                                                   float* __restrict__ sn) {
  const int v = blockIdx.x * 256 + threadIdx.x;
  if (v >= 884736) {
    const int idx = v - 884736;  // < 2304*32
    const int l = idx >> 5;
    const int i = idx & 31;
    const int j = i & 15;
    const float f = __expf(-(float)j * 0.57564627324851142f);
    const float coord = (i < 16) ? (float)(l % HS) : (float)(l / HS);
    const float ang = coord * f;
    cs[idx] = cosf(ang);
    sn[idx] = sinf(ang);
    return;
  }
  const float* src;
  unsigned short* dst;
  int off;
  if (v < 221184)      { src = a0; dst = d0; off = v; }
  else if (v < 294912) { src = a1; dst = d1; off = v - 221184; }
  else if (v < 589824) { src = a2; dst = d2; off = v - 294912; }
  else                 { src = a3; dst = d3; off = v - 589824; }
  const int i = off * 8;
  float4 v0 = *(const float4*)(src + i);
  float4 v1 = *(const float4*)(src + i + 4);
  alignas(16) unsigned short o[8] = {f2b(v0.x), f2b(v0.y), f2b(v0.z), f2b(v0.w),
                                     f2b(v1.x), f2b(v1.y), f2b(v1.z), f2b(v1.w)};
  *(uint4*)(dst + i) = *(const uint4*)o;
}

// ---------------- LayerNorm: fp32 in, bf16 out ----------------
__global__ __launch_bounds__(256) void ln_kernel(const float* __restrict__ x,
                                                 const float* __restrict__ w,
                                                 const float* __restrict__ b,
                                                 unsigned short* __restrict__ out) {
  const int row = blockIdx.x;
  const int t = threadIdx.x;
  const float* xr = x + (size_t)row * CDIM;
  float v0 = xr[t], v1 = xr[t + 256], v2 = xr[t + 512];
  float s = v0 + v1 + v2;
  float ss = v0 * v0 + v1 * v1 + v2 * v2;
#pragma unroll
  for (int off = 32; off > 0; off >>= 1) {
    s += __shfl_down(s, off, 64);
    ss += __shfl_down(ss, off, 64);
  }
  __shared__ float rs[4], rss[4];
  if ((t & 63) == 0) { rs[t >> 6] = s; rss[t >> 6] = ss; }
  __syncthreads();
  float S = rs[0] + rs[1] + rs[2] + rs[3];
  float SS = rss[0] + rss[1] + rss[2] + rss[3];
  const float inv_c = 1.0f / (float)CDIM;
  float mu = S * inv_c;
  float var = SS * inv_c - mu * mu;
  float inv = rsqrtf(var + 1e-5f);
  unsigned short* orow = out + (size_t)row * CDIM;
  orow[t]       = f2b((v0 - mu) * inv * w[t]       + b[t]);
  orow[t + 256] = f2b((v1 - mu) * inv * w[t + 256] + b[t + 256]);
  orow[t + 512] = f2b((v2 - mu) * inv * w[t + 512] + b[t + 512]);
}

// ---------------- bf16 MFMA GEMM, 64x128, BK=32, DOUBLE-buffered ----------------
template <bool GELU, bool RES, bool OUTBF>
__global__ __launch_bounds__(256) void gemm64(const unsigned short* __restrict__ A,
                                              const unsigned short* __restrict__ B,
                                              const float* __restrict__ bias,
                                              const float* __restrict__ res,
                                              void* __restrict__ Cout,
                                              int M, int N, int K) {
  __shared__ unsigned short As[2 * 2048];
  __shared__ unsigned short Bs[2 * 4096];
  const int t = threadIdx.x;
  const int lane = t & 63;
  const int w = t >> 6;
  const int wm = w >> 1, wn = w & 1;
  const int bm = blockIdx.y * 64, bn = blockIdx.x * 128;

  f32x4 acc[2][4] = {};

  const int srow = lane >> 2;
  const int skof = (lane & 3) * 8;
  const unsigned short* Abase = A + (size_t)bm * K + skof;
  const unsigned short* Bbase = B + (size_t)bn * K + skof;
  const int lr = lane & 15, lk = (lane >> 4) * 8, lg = lane >> 4;
  const int nk = K >> 5;

  gld_lds16(As + w * 512, Abase + (size_t)(w * 16 + srow) * K);
  gld_lds16(Bs + w * 512, Bbase + (size_t)(w * 16 + srow) * K);
  gld_lds16(Bs + (4 + w) * 512, Bbase + (size_t)((4 + w) * 16 + srow) * K);
  __syncthreads();

#pragma unroll 1
  for (int ks = 0; ks < nk; ++ks) {
    const int offA = (ks & 1) * 2048;
    const int offB = (ks & 1) * 4096;
    if (ks + 1 < nk) {
      const int nA = 2048 - offA, nB = 4096 - offB;
      const int k1 = (ks + 1) * 32;
      gld_lds16(As + nA + w * 512, Abase + (size_t)(w * 16 + srow) * K + k1);
      gld_lds16(Bs + nB + w * 512, Bbase + (size_t)(w * 16 + srow) * K + k1);
      gld_lds16(Bs + nB + (4 + w) * 512, Bbase + (size_t)((4 + w) * 16 + srow) * K + k1);
    }
    s16x8 a[2], b[4];
#pragma unroll
    for (int m = 0; m < 2; ++m)
      a[m] = *(const s16x8*)&As[offA + (wm * 32 + m * 16 + lr) * 32 + lk];
#pragma unroll
    for (int n = 0; n < 4; ++n)
      b[n] = *(const s16x8*)&Bs[offB + (wn * 64 + n * 16 + lr) * 32 + lk];
    __builtin_amdgcn_s_setprio(1);
#pragma unroll
    for (int m = 0; m < 2; ++m)
#pragma unroll
      for (int n = 0; n < 4; ++n)
        acc[m][n] = __builtin_amdgcn_mfma_f32_16x16x32_bf16(a[m], b[n], acc[m][n], 0, 0, 0);
    __builtin_amdgcn_s_setprio(0);
    __syncthreads();
  }

#pragma unroll
  for (int n = 0; n < 4; ++n) {
    const int col = bn + wn * 64 + n * 16 + lr;
    const float bc = bias[col];
#pragma unroll
    for (int m = 0; m < 2; ++m) {
#pragma unroll
      for (int j = 0; j < 4; ++j) {
        const int row = bm + wm * 32 + m * 16 + lg * 4 + j;
        float v = acc[m][n][j] + bc;
        if (GELU) v = 0.5f * v * (1.0f + erff(v * 0.70710678118654752f));
        if (RES) v += res[(size_t)row * N + col];
        if (OUTBF) ((unsigned short*)Cout)[(size_t)row * N + col] = f2b(v);
        else       ((float*)Cout)[(size_t)row * N + col] = v;
      }
    }
  }
}

// ---------------- bf16 MFMA GEMM, 64x128, BK=64, DOUBLE-buffered ----------------
// Halves the barrier count; 48KB LDS still allows 3 blocks/CU.
template <bool GELU, bool RES, bool OUTBF>
__global__ __launch_bounds__(256) void gemm64k64(const unsigned short* __restrict__ A,
                                                 const unsigned short* __restrict__ B,
                                                 const float* __restrict__ bias,
                                                 const float* __restrict__ res,
                                                 void* __restrict__ Cout,
                                                 int M, int N, int K) {
  __shared__ unsigned short As[2 * 4096];
  __shared__ unsigned short Bs[2 * 8192];
  const int t = threadIdx.x;
  const int lane = t & 63;
  const int w = t >> 6;
  const int wm = w >> 1, wn = w & 1;
  const int bm = blockIdx.y * 64, bn = blockIdx.x * 128;

  f32x4 acc[2][4] = {};

  const int srow = lane >> 3;          // row within 8-row chunk
  const int skof = (lane & 7) * 8;     // k-offset (shorts)
  const unsigned short* Abase = A + (size_t)bm * K + skof;
  const unsigned short* Bbase = B + (size_t)bn * K + skof;
  const int ca0 = 2 * w, ca1 = 2 * w + 1;
  const int cb0 = 4 * w, cb1 = 4 * w + 1, cb2 = 4 * w + 2, cb3 = 4 * w + 3;
  const int lr = lane & 15, lk = (lane >> 4) * 8, lg = lane >> 4;
  const int nk = K >> 6;

  gld_lds16(As + ca0 * 512, Abase + (size_t)(ca0 * 8 + srow) * K);
  gld_lds16(As + ca1 * 512, Abase + (size_t)(ca1 * 8 + srow) * K);
  gld_lds16(Bs + cb0 * 512, Bbase + (size_t)(cb0 * 8 + srow) * K);
  gld_lds16(Bs + cb1 * 512, Bbase + (size_t)(cb1 * 8 + srow) * K);
  gld_lds16(Bs + cb2 * 512, Bbase + (size_t)(cb2 * 8 + srow) * K);
  gld_lds16(Bs + cb3 * 512, Bbase + (size_t)(cb3 * 8 + srow) * K);
  __syncthreads();

#pragma unroll 1
  for (int ks = 0; ks < nk; ++ks) {
    const int offA = (ks & 1) * 4096;
    const int offB = (ks & 1) * 8192;
    if (ks + 1 < nk) {
      const int nA = 4096 - offA, nB = 8192 - offB;
      const int k1 = (ks + 1) * 64;
      gld_lds16(As + nA + ca0 * 512, Abase + (size_t)(ca0 * 8 + srow) * K + k1);
      gld_lds16(As + nA + ca1 * 512, Abase + (size_t)(ca1 * 8 + srow) * K + k1);
      gld_lds16(Bs + nB + cb0 * 512, Bbase + (size_t)(cb0 * 8 + srow) * K + k1);
      gld_lds16(Bs + nB + cb1 * 512, Bbase + (size_t)(cb1 * 8 + srow) * K + k1);
      gld_lds16(Bs + nB + cb2 * 512, Bbase + (size_t)(cb2 * 8 + srow) * K + k1);
      gld_lds16(Bs + nB + cb3 * 512, Bbase + (size_t)(cb3 * 8 + srow) * K + k1);
    }
#pragma unroll
    for (int kk = 0; kk < 2; ++kk) {
      s16x8 a[2], b[4];
#pragma unroll
      for (int m = 0; m < 2; ++m)
        a[m] = *(const s16x8*)&As[offA + (wm * 32 + m * 16 + lr) * 64 + kk * 32 + lk];
#pragma unroll
      for (int n = 0; n < 4; ++n)
        b[n] = *(const s16x8*)&Bs[offB + (wn * 64 + n * 16 + lr) * 64 + kk * 32 + lk];
      __builtin_amdgcn_s_setprio(1);
#pragma unroll
      for (int m = 0; m < 2; ++m)
#pragma unroll
        for (int n = 0; n < 4; ++n)
          acc[m][n] = __builtin_amdgcn_mfma_f32_16x16x32_bf16(a[m], b[n], acc[m][n], 0, 0, 0);
      __builtin_amdgcn_s_setprio(0);
    }
    __syncthreads();
  }

#pragma unroll
  for (int n = 0; n < 4; ++n) {
    const int col = bn + wn * 64 + n * 16 + lr;
    const float bc = bias[col];
#pragma unroll
    for (int m = 0; m < 2; ++m) {
#pragma unroll
      for (int j = 0; j < 4; ++j) {
        const int row = bm + wm * 32 + m * 16 + lg * 4 + j;
        float v = acc[m][n][j] + bc;
        if (GELU) v = 0.5f * v * (1.0f + erff(v * 0.70710678118654752f));
        if (RES) v += res[(size_t)row * N + col];
        if (OUTBF) ((unsigned short*)Cout)[(size_t)row * N + col] = f2b(v);
        else       ((float*)Cout)[(size_t)row * N + col] = v;
      }
    }
  }
}

// ---------------- prep: qkv -> Qb (x0.125, RoPE), Kb (RoPE), Vb subtiled -----------
__global__ __launch_bounds__(256) void prep_kernel(const float* __restrict__ qkv,
                                                   const float* __restrict__ cs,
                                                   const float* __restrict__ sn,
                                                   unsigned short* __restrict__ Qb,
                                                   unsigned short* __restrict__ Kb,
                                                   unsigned short* __restrict__ Vb) {
  __shared__ unsigned short Vs[64 * 72];
  const int t = threadIdx.x;
  const int l0 = blockIdx.x * 64, n = blockIdx.y;
  const int r = t >> 2, c = t & 3;
  const int l = l0 + r;
  const float* base = qkv + (size_t)l * (3 * CDIM) + n * HDIM + c * 16;
#pragma unroll
  for (int pq = 0; pq < 2; ++pq) {
    const float* src = base + pq * CDIM;
    const float qs = pq ? 1.0f : 0.125f;
    alignas(16) unsigned short o[16];
#pragma unroll
    for (int i = 0; i < 4; ++i) {
      float4 v = *(const float4*)(src + i * 4);
      const int pr = c * 8 + i * 2;
      const float c0 = cs[l * 32 + pr],     s0 = sn[l * 32 + pr];
      const float c1 = cs[l * 32 + pr + 1], s1 = sn[l * 32 + pr + 1];
      o[i * 4 + 0] = f2b((v.x * c0 - v.y * s0) * qs);
      o[i * 4 + 1] = f2b((v.x * s0 + v.y * c0) * qs);
      o[i * 4 + 2] = f2b((v.z * c1 - v.w * s1) * qs);
      o[i * 4 + 3] = f2b((v.z * s1 + v.w * c1) * qs);
    }
    unsigned short* dst = (pq ? Kb : Qb) + ((size_t)n * LTOK + l) * HDIM + c * 16;
    *(uint4*)dst = *(const uint4*)o;
    *(uint4*)(dst + 8) = *(const uint4*)(o + 8);
  }
  // V transpose via LDS, then write subtiled [kc][d][8]
  {
    const float* vsrc = base + 2 * CDIM;
    alignas(16) unsigned short vo[16];
#pragma unroll
    for (int i = 0; i < 4; ++i) {
      float4 v = *(const float4*)(vsrc + i * 4);
      vo[i * 4 + 0] = f2b(v.x); vo[i * 4 + 1] = f2b(v.y);
      vo[i * 4 + 2] = f2b(v.z); vo[i * 4 + 3] = f2b(v.w);
    }
    *(uint4*)&Vs[r * 72 + c * 16] = *(const uint4*)vo;
    *(uint4*)&Vs[r * 72 + c * 16 + 8] = *(const uint4*)(vo + 8);
  }
  __syncthreads();
  {
    const int d = t >> 2, kc16 = (t & 3) * 16;
    alignas(16) unsigned short o[16];
#pragma unroll
    for (int i = 0; i < 16; ++i) o[i] = Vs[(kc16 + i) * 72 + d];
    const int kb = (l0 + kc16) >> 3;  // global key-chunk
    unsigned short* dst0 = Vb + ((size_t)(n * (LTOK / 8) + kb) * 64 + d) * 8;
    unsigned short* dst1 = Vb + ((size_t)(n * (LTOK / 8) + kb + 1) * 64 + d) * 8;
    *(uint4*)dst0 = *(const uint4*)o;
    *(uint4*)dst1 = *(const uint4*)(o + 8);
  }
}

// ---------------- MFMA flash attention: KVB=96 dbuf + XCD swizzle ----------------
// (R11/R14 kernel + bijective XCD swizzle: 432 = 8 x 54; FETCH 30->6.7MB)
__global__ __launch_bounds__(256) void attn_mfma(const unsigned short* __restrict__ Qb,
                                                 const unsigned short* __restrict__ Kb,
                                                 const unsigned short* __restrict__ Vb,
                                                 const float* __restrict__ relh,
                                                 const float* __restrict__ relw,
                                                 unsigned short* __restrict__ out) {
  __shared__ __align__(16) unsigned char smem[74752];
  unsigned short* const K_lds = (unsigned short*)(smem);           // +b*6144 shorts
  unsigned short* const V_lds = (unsigned short*)(smem + 24576);   // +b*7168 shorts
  unsigned short* const P_lds = (unsigned short*)(smem + 53248);
  float* const bh_t = (float*)(smem + 62464);
  unsigned short* const Q_s = (unsigned short*)(smem + 53248);     // overlays P

  const int t = threadIdx.x;
  const int lane = t & 63, w = t >> 6;
  const int p = lane & 15, g = lane >> 4;
  const int bid = blockIdx.x;
  const int swz = (bid & 7) * 54 + (bid >> 3);   // bijective: 432 = 8 * 54
  const int l0 = (swz % 36) * 64, n = swz / 36;

  const unsigned short* Khead = Kb + (size_t)n * LTOK * HDIM;
  const unsigned short* Vhead = Vb + (size_t)n * (LTOK / 8) * 64 * 8;

  // ---- stage Q into padded Q_s (overlays P) ----
  {
    const int r = t >> 2, c = t & 3;
    const unsigned short* src = Qb + ((size_t)n * LTOK + l0 + r) * HDIM + c * 16;
    uint4 v0 = *(const uint4*)src;
    uint4 v1 = *(const uint4*)(src + 8);
    *(uint4*)&Q_s[r * 72 + c * 16] = v0;
    *(uint4*)&Q_s[r * 72 + c * 16 + 8] = v1;
  }
  __syncthreads();

  // ---- staging geometry ----
  const int rowb = lane >> 3;
  const int srcc = (lane & 7) ^ rowb;
  const int kc0 = w, kc1 = w + 4, kc2 = w + 8;   // this wave's chunks (of 12)

  // issue tile-0 stage into buffer 0 (latency hides under bias compute)
  {
    gld_lds16(K_lds + kc0 * 512, Khead + (size_t)(kc0 * 8 + rowb) * HDIM + srcc * 8);
    gld_lds16(K_lds + kc1 * 512, Khead + (size_t)(kc1 * 8 + rowb) * HDIM + srcc * 8);
    gld_lds16(K_lds + kc2 * 512, Khead + (size_t)(kc2 * 8 + rowb) * HDIM + srcc * 8);
    gld_lds16(V_lds + kc0 * 512, Vhead + kc0 * 512 + lane * 8);
    gld_lds16(V_lds + kc1 * 512, Vhead + kc1 * 512 + lane * 8);
    gld_lds16(V_lds + kc2 * 512, Vhead + kc2 * 512 + lane * 8);
  }
  // zero V pad keychunks 12,13 of BOTH buffers
  if (t < 128) *(uint4*)&V_lds[6144 + t * 8] = uint4{0u, 0u, 0u, 0u};
  else         *(uint4*)&V_lds[7168 + 6144 + (t - 128) * 8] = uint4{0u, 0u, 0u, 0u};

  const s16x8 qf0 = *(const s16x8*)&Q_s[(w * 16 + p) * 72 + g * 8];
  const s16x8 qf1 = *(const s16x8*)&Q_s[(w * 16 + p) * 72 + 32 + g * 8];

  const int qh_lane = (l0 + lane) / 48;
#pragma unroll
  for (int i = 0; i < 12; ++i) {
    const int kh = w + 4 * i;
    const float* rrow = relh + (size_t)(qh_lane - kh + 47) * HDIM;
    float acc = 0.f;
#pragma unroll
    for (int c8 = 0; c8 < 8; ++c8) {
      s16x8 qv = *(const s16x8*)&Q_s[lane * 72 + c8 * 8];
      float4 ra = *(const float4*)&rrow[c8 * 8];
      float4 rb = *(const float4*)&rrow[c8 * 8 + 4];
      acc += b2f((unsigned short)qv[0]) * ra.x + b2f((unsigned short)qv[1]) * ra.y +
             b2f((unsigned short)qv[2]) * ra.z + b2f((unsigned short)qv[3]) * ra.w +
             b2f((unsigned short)qv[4]) * rb.x + b2f((unsigned short)qv[5]) * rb.y +
             b2f((unsigned short)qv[6]) * rb.z + b2f((unsigned short)qv[7]) * rb.w;
    }
    bh_t[kh * 64 + lane] = acc * 8.0f;   // undo Q prescale
  }

  float bwreg[12];
  {
    const int qrow = w * 16 + p;
    const int qw_lane = (l0 + qrow) % 48;
#pragma unroll
    for (int mb = 0; mb < 3; ++mb)
#pragma unroll
      for (int jj = 0; jj < 4; ++jj) {
        const int j = 16 * mb + 4 * g + jj;
        const float* rrow = relw + (size_t)(qw_lane - j + 47) * HDIM;
        float acc = 0.f;
#pragma unroll
        for (int c8 = 0; c8 < 8; ++c8) {
          s16x8 qv = *(const s16x8*)&Q_s[qrow * 72 + c8 * 8];
          float4 ra = *(const float4*)&rrow[c8 * 8];
          float4 rb = *(const float4*)&rrow[c8 * 8 + 4];
          acc += b2f((unsigned short)qv[0]) * ra.x + b2f((unsigned short)qv[1]) * ra.y +
                 b2f((unsigned short)qv[2]) * ra.z + b2f((unsigned short)qv[3]) * ra.w +
                 b2f((unsigned short)qv[4]) * rb.x + b2f((unsigned short)qv[5]) * rb.y +
                 b2f((unsigned short)qv[6]) * rb.z + b2f((unsigned short)qv[7]) * rb.w;
        }
        bwreg[mb * 4 + jj] = acc * 8.0f;
      }
  }
  __syncthreads();  // Q dead; tile-0 loads drained; V pads visible

  // P zero pads (keys [48,64) per row)
  {
    uint2 z = {0u, 0u};
    *(uint2*)&P_lds[(w * 16 + p) * 72 + 48 + 4 * g] = z;
  }

  float lsum = 0.f;
  f32x4 accO[4] = {};
  const int sw0 = g ^ (p & 7);
  const int sw1 = (g + 4) ^ (p & 7);
  unsigned short* const Pw = P_lds + w * 16 * 72;

#pragma unroll 1
  for (int kt = 0; kt < 24; ++kt) {
    const int ko = (kt & 1) * 6144;
    const int vo = (kt & 1) * 7168;
    if (kt < 23) {
      const int nko = 6144 - ko, nvo = 7168 - vo;
      const int kb = (kt + 1) * 96;
      const int vb = (kt + 1) * 12;
      gld_lds16(K_lds + nko + kc0 * 512, Khead + (size_t)(kb + kc0 * 8 + rowb) * HDIM + srcc * 8);
      gld_lds16(K_lds + nko + kc1 * 512, Khead + (size_t)(kb + kc1 * 8 + rowb) * HDIM + srcc * 8);
      gld_lds16(K_lds + nko + kc2 * 512, Khead + (size_t)(kb + kc2 * 8 + rowb) * HDIM + srcc * 8);
      gld_lds16(V_lds + nvo + kc0 * 512, Vhead + (vb + kc0) * 512 + lane * 8);
      gld_lds16(V_lds + nvo + kc1 * 512, Vhead + (vb + kc1) * 512 + lane * 8);
      gld_lds16(V_lds + nvo + kc2 * 512, Vhead + (vb + kc2) * 512 + lane * 8);
    }

#pragma unroll 1
    for (int h = 0; h < 2; ++h) {
      f32x4 st[3] = {};
      __builtin_amdgcn_s_setprio(1);
#pragma unroll
      for (int mb = 0; mb < 3; ++mb) {
        const int krow = ko + (h * 48 + 16 * mb + p) * 64;
        s16x8 kf0 = *(const s16x8*)&K_lds[krow + sw0 * 8];
        s16x8 kf1 = *(const s16x8*)&K_lds[krow + sw1 * 8];
        st[mb] = __builtin_amdgcn_mfma_f32_16x16x32_bf16(kf0, qf0, st[mb], 0, 0, 0);
        st[mb] = __builtin_amdgcn_mfma_f32_16x16x32_bf16(kf1, qf1, st[mb], 0, 0, 0);
      }
      __builtin_amdgcn_s_setprio(0);

      const float bhv = bh_t[(2 * kt + h) * 64 + w * 16 + p] - 8.0f;
      float pv[12], ps = 0.f;
#pragma unroll
      for (int mb = 0; mb < 3; ++mb)
#pragma unroll
        for (int jj = 0; jj < 4; ++jj) {
          const float sv = st[mb][jj] + bhv + bwreg[mb * 4 + jj];
          pv[mb * 4 + jj] = __expf(sv);
          ps += pv[mb * 4 + jj];
        }
      lsum += ps;

#pragma unroll
      for (int mb = 0; mb < 3; ++mb) {
        unsigned int lo = (unsigned int)f2b(pv[mb * 4 + 0]) | ((unsigned int)f2b(pv[mb * 4 + 1]) << 16);
        unsigned int hi = (unsigned int)f2b(pv[mb * 4 + 2]) | ((unsigned int)f2b(pv[mb * 4 + 3]) << 16);
        uint2 val = {lo, hi};
        *(uint2*)&Pw[p * 72 + 16 * mb + 4 * g] = val;
      }

      const s16x8 pf0 = *(const s16x8*)&Pw[p * 72 + g * 8];
      const s16x8 pf1 = *(const s16x8*)&Pw[p * 72 + 32 + g * 8];
      __builtin_amdgcn_s_setprio(1);
#pragma unroll
      for (int db = 0; db < 4; ++db) {
        const int drow = 16 * db + p;
        s16x8 vf0 = *(const s16x8*)&V_lds[vo + ((6 * h + g) * 64 + drow) * 8];
        s16x8 vf1 = *(const s16x8*)&V_lds[vo + ((6 * h + 4 + g) * 64 + drow) * 8];
        accO[db] = __builtin_amdgcn_mfma_f32_16x16x32_bf16(vf0, pf0, accO[db], 0, 0, 0);
        accO[db] = __builtin_amdgcn_mfma_f32_16x16x32_bf16(vf1, pf1, accO[db], 0, 0, 0);
      }
      __builtin_amdgcn_s_setprio(0);
    }

    __syncthreads();
  }

  // epilogue
  float ls = lsum + __shfl_xor(lsum, 16, 64);
  ls += __shfl_xor(ls, 32, 64);
  const float inv = 1.0f / ls;
  unsigned short* orow = out + (size_t)(l0 + w * 16 + p) * CDIM + n * HDIM;
#pragma unroll
  for (int db = 0; db < 4; ++db) {
    unsigned int lo = (unsigned int)f2b(accO[db][0] * inv) | ((unsigned int)f2b(accO[db][1] * inv) << 16);
    unsigned int hi = (unsigned int)f2b(accO[db][2] * inv) | ((unsigned int)f2b(accO[db][3] * inv) << 16);
    uint2 val = {lo, hi};
    *(uint2*)&orow[16 * db + 4 * g] = val;
  }
}

// ---------------- launch ----------------
extern "C" void kernel_launch(void* const* d_in, const int* in_sizes, int n_in,
                              void* d_out, int out_size, void* d_ws, size_t ws_size,
                              hipStream_t stream) {
  const float* x     = (const float*)d_in[0];
  const float* ln1w  = (const float*)d_in[1];
  const float* ln1b  = (const float*)d_in[2];
  const float* qkvw  = (const float*)d_in[3];
  const float* qkvb  = (const float*)d_in[4];
  const float* relh  = (const float*)d_in[5];
  const float* relw  = (const float*)d_in[6];
  const float* projw = (const float*)d_in[7];
  const float* projb = (const float*)d_in[8];
  const float* ln2w  = (const float*)d_in[9];
  const float* ln2b  = (const float*)d_in[10];
  const float* fc1w  = (const float*)d_in[11];
  const float* fc1b  = (const float*)d_in[12];
  const float* fc2w  = (const float*)d_in[13];
  const float* fc2b  = (const float*)d_in[14];
  float* out = (float*)d_out;
  float* ws = (float*)d_ws;

  float* qkv = ws;                             // L*3C f32
  float* x1  = qkv + (size_t)LTOK * 3 * CDIM;  // L*C f32 (overlaid by Qb/Kb before proj)
  float* cs  = x1 + (size_t)LTOK * CDIM;
  float* sn  = cs + (size_t)LTOK * 32;
  unsigned short* h_bf    = (unsigned short*)(sn + (size_t)LTOK * 32);
  unsigned short* attn_bf = h_bf + (size_t)LTOK * CDIM;
  unsigned short* wq      = attn_bf + (size_t)LTOK * CDIM;
  unsigned short* wproj   = wq + (size_t)3 * CDIM * CDIM;
  unsigned short* wfc1    = wproj + (size_t)CDIM * CDIM;
  unsigned short* wfc2    = wfc1 + (size_t)4 * CDIM * CDIM;
  unsigned short* Qb      = (unsigned short*)x1;   // Qb+Kb fit x1 exactly
  unsigned short* Kb      = Qb + (size_t)NHEAD * LTOK * HDIM;
  unsigned short* Vb      = wq;                    // overlay: wq dead after qkv GEMM
  unsigned short* m1_bf   = (unsigned short*)qkv;  // overlay: qkv dead after prep

  // weight conversions + rope table (single fused launch; 958464 threads)
  f2b5_kernel<<<3744, 256, 0, stream>>>(qkvw, projw, fc1w, fc2w, wq, wproj, wfc1, wfc2,
                                        cs, sn);

  ln_kernel<<<LTOK, 256, 0, stream>>>(x, ln1w, ln1b, h_bf);
  gemm64<false, false, false><<<dim3(18, 36), 256, 0, stream>>>(
      h_bf, wq, qkvb, nullptr, qkv, LTOK, 3 * CDIM, CDIM);
  prep_kernel<<<dim3(36, 12), 256, 0, stream>>>(qkv, cs, sn, Qb, Kb, Vb);
  attn_mfma<<<432, 256, 0, stream>>>(Qb, Kb, Vb, relh, relw, attn_bf);
  gemm64k64<false, true, false><<<dim3(6, 36), 256, 0, stream>>>(
      attn_bf, wproj, projb, x, x1, LTOK, CDIM, CDIM);
  ln_kernel<<<LTOK, 256, 0, stream>>>(x1, ln2w, ln2b, h_bf);
  gemm64k64<true, false, true><<<dim3(24, 36), 256, 0, stream>>>(
      h_bf, wfc1, fc1b, nullptr, m1_bf, LTOK, 4 * CDIM, CDIM);
  gemm64k64<false, true, false><<<dim3(6, 36), 256, 0, stream>>>(
      m1_bf, wfc2, fc2b, x1, out, LTOK, CDIM, 4 * CDIM);
}

// Round 20
// 235.484 us; speedup vs baseline: 1.0168x; 1.0168x over previous
//
#include <hip/hip_runtime.h>
#include <math.h>

#define LTOK 2304
#define CDIM 768
#define NHEAD 12
#define HDIM 64
#define HS 48

typedef short s16x8 __attribute__((ext_vector_type(8)));   // 8 bf16 bits (4 VGPRs)
typedef float f32x4 __attribute__((ext_vector_type(4)));

__device__ __forceinline__ unsigned short f2b(float f) {
  __bf16 b = (__bf16)f;   // RNE
  return __builtin_bit_cast(unsigned short, b);
}
__device__ __forceinline__ float b2f(unsigned short u) {
  unsigned int x = ((unsigned int)u) << 16;
  return __builtin_bit_cast(float, x);
}

__device__ __forceinline__ void gld_lds16(void* lds, const void* g) {
  __builtin_amdgcn_global_load_lds(
      (const __attribute__((address_space(1))) unsigned int*)g,
      (__attribute__((address_space(3))) unsigned int*)lds, 16, 0, 0);
}

// ---------------- fused fp32 -> bf16 convert of all 4 weight tensors ----------------
__global__ __launch_bounds__(256) void f2b4_kernel(const float* __restrict__ a0,
                                                   const float* __restrict__ a1,
                                                   const float* __restrict__ a2,
                                                   const float* __restrict__ a3,
                                                   unsigned short* __restrict__ d0,
                                                   unsigned short* __restrict__ d1,
                                                   unsigned short* __restrict__ d2,
                                                   unsigned short* __restrict__ d3) {
  const int v = blockIdx.x * 256 + threadIdx.x;
  const float* src;
  unsigned short* dst;
  int off;
  if (v < 221184)      { src = a0; dst = d0; off = v; }
  else if (v < 294912) { src = a1; dst = d1; off = v - 221184; }
  else if (v < 589824) { src = a2; dst = d2; off = v - 294912; }
  else                 { src = a3; dst = d3; off = v - 589824; }
  const int i = off * 8;
  float4 v0 = *(const float4*)(src + i);
  float4 v1 = *(const float4*)(src + i + 4);
  alignas(16) unsigned short o[8] = {f2b(v0.x), f2b(v0.y), f2b(v0.z), f2b(v0.w),
                                     f2b(v1.x), f2b(v1.y), f2b(v1.z), f2b(v1.w)};
  *(uint4*)(dst + i) = *(const uint4*)o;
}

// ---------------- LayerNorm: fp32 in, bf16 out ----------------
__global__ __launch_bounds__(256) void ln_kernel(const float* __restrict__ x,
                                                 const float* __restrict__ w,
                                                 const float* __restrict__ b,
                                                 unsigned short* __restrict__ out) {
  const int row = blockIdx.x;
  const int t = threadIdx.x;
  const float* xr = x + (size_t)row * CDIM;
  float v0 = xr[t], v1 = xr[t + 256], v2 = xr[t + 512];
  float s = v0 + v1 + v2;
  float ss = v0 * v0 + v1 * v1 + v2 * v2;
#pragma unroll
  for (int off = 32; off > 0; off >>= 1) {
    s += __shfl_down(s, off, 64);
    ss += __shfl_down(ss, off, 64);
  }
  __shared__ float rs[4], rss[4];
  if ((t & 63) == 0) { rs[t >> 6] = s; rss[t >> 6] = ss; }
  __syncthreads();
  float S = rs[0] + rs[1] + rs[2] + rs[3];
  float SS = rss[0] + rss[1] + rss[2] + rss[3];
  const float inv_c = 1.0f / (float)CDIM;
  float mu = S * inv_c;
  float var = SS * inv_c - mu * mu;
  float inv = rsqrtf(var + 1e-5f);
  unsigned short* orow = out + (size_t)row * CDIM;
  orow[t]       = f2b((v0 - mu) * inv * w[t]       + b[t]);
  orow[t + 256] = f2b((v1 - mu) * inv * w[t + 256] + b[t + 256]);
  orow[t + 512] = f2b((v2 - mu) * inv * w[t + 512] + b[t + 512]);
}

// ---------------- bf16 MFMA GEMM, 64x128, BK=32, DOUBLE-buffered ----------------
template <bool GELU, bool RES, bool OUTBF>
__global__ __launch_bounds__(256) void gemm64(const unsigned short* __restrict__ A,
                                              const unsigned short* __restrict__ B,
                                              const float* __restrict__ bias,
                                              const float* __restrict__ res,
                                              void* __restrict__ Cout,
                                              int M, int N, int K) {
  __shared__ unsigned short As[2 * 2048];
  __shared__ unsigned short Bs[2 * 4096];
  const int t = threadIdx.x;
  const int lane = t & 63;
  const int w = t >> 6;
  const int wm = w >> 1, wn = w & 1;
  const int bm = blockIdx.y * 64, bn = blockIdx.x * 128;

  f32x4 acc[2][4] = {};

  const int srow = lane >> 2;
  const int skof = (lane & 3) * 8;
  const unsigned short* Abase = A + (size_t)bm * K + skof;
  const unsigned short* Bbase = B + (size_t)bn * K + skof;
  const int lr = lane & 15, lk = (lane >> 4) * 8, lg = lane >> 4;
  const int nk = K >> 5;

  gld_lds16(As + w * 512, Abase + (size_t)(w * 16 + srow) * K);
  gld_lds16(Bs + w * 512, Bbase + (size_t)(w * 16 + srow) * K);
  gld_lds16(Bs + (4 + w) * 512, Bbase + (size_t)((4 + w) * 16 + srow) * K);
  __syncthreads();

#pragma unroll 1
  for (int ks = 0; ks < nk; ++ks) {
    const int offA = (ks & 1) * 2048;
    const int offB = (ks & 1) * 4096;
    if (ks + 1 < nk) {
      const int nA = 2048 - offA, nB = 4096 - offB;
      const int k1 = (ks + 1) * 32;
      gld_lds16(As + nA + w * 512, Abase + (size_t)(w * 16 + srow) * K + k1);
      gld_lds16(Bs + nB + w * 512, Bbase + (size_t)(w * 16 + srow) * K + k1);
      gld_lds16(Bs + nB + (4 + w) * 512, Bbase + (size_t)((4 + w) * 16 + srow) * K + k1);
    }
    s16x8 a[2], b[4];
#pragma unroll
    for (int m = 0; m < 2; ++m)
      a[m] = *(const s16x8*)&As[offA + (wm * 32 + m * 16 + lr) * 32 + lk];
#pragma unroll
    for (int n = 0; n < 4; ++n)
      b[n] = *(const s16x8*)&Bs[offB + (wn * 64 + n * 16 + lr) * 32 + lk];
    __builtin_amdgcn_s_setprio(1);
#pragma unroll
    for (int m = 0; m < 2; ++m)
#pragma unroll
      for (int n = 0; n < 4; ++n)
        acc[m][n] = __builtin_amdgcn_mfma_f32_16x16x32_bf16(a[m], b[n], acc[m][n], 0, 0, 0);
    __builtin_amdgcn_s_setprio(0);
    __syncthreads();
  }

#pragma unroll
  for (int n = 0; n < 4; ++n) {
    const int col = bn + wn * 64 + n * 16 + lr;
    const float bc = bias[col];
#pragma unroll
    for (int m = 0; m < 2; ++m) {
#pragma unroll
      for (int j = 0; j < 4; ++j) {
        const int row = bm + wm * 32 + m * 16 + lg * 4 + j;
        float v = acc[m][n][j] + bc;
        if (GELU) v = 0.5f * v * (1.0f + erff(v * 0.70710678118654752f));
        if (RES) v += res[(size_t)row * N + col];
        if (OUTBF) ((unsigned short*)Cout)[(size_t)row * N + col] = f2b(v);
        else       ((float*)Cout)[(size_t)row * N + col] = v;
      }
    }
  }
}

// ---------------- RoPE cos/sin tables: [L][32] ----------------
__global__ __launch_bounds__(256) void rope_cs_kernel(float* __restrict__ cs,
                                                      float* __restrict__ sn) {
  const int idx = blockIdx.x * 256 + threadIdx.x;  // < 2304*32
  const int l = idx >> 5;
  const int i = idx & 31;
  const int j = i & 15;
  const float f = __expf(-(float)j * 0.57564627324851142f);
  const float coord = (i < 16) ? (float)(l % HS) : (float)(l / HS);
  const float ang = coord * f;
  cs[idx] = cosf(ang);
  sn[idx] = sinf(ang);
}

// ---------------- prep: qkv -> Qb (x0.125, RoPE), Kb (RoPE), Vb subtiled -----------
__global__ __launch_bounds__(256) void prep_kernel(const float* __restrict__ qkv,
                                                   const float* __restrict__ cs,
                                                   const float* __restrict__ sn,
                                                   unsigned short* __restrict__ Qb,
                                                   unsigned short* __restrict__ Kb,
                                                   unsigned short* __restrict__ Vb) {
  __shared__ unsigned short Vs[64 * 72];
  const int t = threadIdx.x;
  const int l0 = blockIdx.x * 64, n = blockIdx.y;
  const int r = t >> 2, c = t & 3;
  const int l = l0 + r;
  const float* base = qkv + (size_t)l * (3 * CDIM) + n * HDIM + c * 16;
#pragma unroll
  for (int pq = 0; pq < 2; ++pq) {
    const float* src = base + pq * CDIM;
    const float qs = pq ? 1.0f : 0.125f;
    alignas(16) unsigned short o[16];
#pragma unroll
    for (int i = 0; i < 4; ++i) {
      float4 v = *(const float4*)(src + i * 4);
      const int pr = c * 8 + i * 2;
      const float c0 = cs[l * 32 + pr],     s0 = sn[l * 32 + pr];
      const float c1 = cs[l * 32 + pr + 1], s1 = sn[l * 32 + pr + 1];
      o[i * 4 + 0] = f2b((v.x * c0 - v.y * s0) * qs);
      o[i * 4 + 1] = f2b((v.x * s0 + v.y * c0) * qs);
      o[i * 4 + 2] = f2b((v.z * c1 - v.w * s1) * qs);
      o[i * 4 + 3] = f2b((v.z * s1 + v.w * c1) * qs);
    }
    unsigned short* dst = (pq ? Kb : Qb) + ((size_t)n * LTOK + l) * HDIM + c * 16;
    *(uint4*)dst = *(const uint4*)o;
    *(uint4*)(dst + 8) = *(const uint4*)(o + 8);
  }
  // V transpose via LDS, then write subtiled [kc][d][8]
  {
    const float* vsrc = base + 2 * CDIM;
    alignas(16) unsigned short vo[16];
#pragma unroll
    for (int i = 0; i < 4; ++i) {
      float4 v = *(const float4*)(vsrc + i * 4);
      vo[i * 4 + 0] = f2b(v.x); vo[i * 4 + 1] = f2b(v.y);
      vo[i * 4 + 2] = f2b(v.z); vo[i * 4 + 3] = f2b(v.w);
    }
    *(uint4*)&Vs[r * 72 + c * 16] = *(const uint4*)vo;
    *(uint4*)&Vs[r * 72 + c * 16 + 8] = *(const uint4*)(vo + 8);
  }
  __syncthreads();
  {
    const int d = t >> 2, kc16 = (t & 3) * 16;
    alignas(16) unsigned short o[16];
#pragma unroll
    for (int i = 0; i < 16; ++i) o[i] = Vs[(kc16 + i) * 72 + d];
    const int kb = (l0 + kc16) >> 3;  // global key-chunk
    unsigned short* dst0 = Vb + ((size_t)(n * (LTOK / 8) + kb) * 64 + d) * 8;
    unsigned short* dst1 = Vb + ((size_t)(n * (LTOK / 8) + kb + 1) * 64 + d) * 8;
    *(uint4*)dst0 = *(const uint4*)o;
    *(uint4*)dst1 = *(const uint4*)(o + 8);
  }
}

// ---------------- MFMA flash attention: KVB=96 dbuf + XCD swizzle ----------------
// (R11/R14 kernel + bijective XCD swizzle: 432 = 8 x 54; FETCH 30->6.7MB)
__global__ __launch_bounds__(256) void attn_mfma(const unsigned short* __restrict__ Qb,
                                                 const unsigned short* __restrict__ Kb,
                                                 const unsigned short* __restrict__ Vb,
                                                 const float* __restrict__ relh,
                                                 const float* __restrict__ relw,
                                                 unsigned short* __restrict__ out) {
  __shared__ __align__(16) unsigned char smem[74752];
  unsigned short* const K_lds = (unsigned short*)(smem);           // +b*6144 shorts
  unsigned short* const V_lds = (unsigned short*)(smem + 24576);   // +b*7168 shorts
  unsigned short* const P_lds = (unsigned short*)(smem + 53248);
  float* const bh_t = (float*)(smem + 62464);
  unsigned short* const Q_s = (unsigned short*)(smem + 53248);     // overlays P

  const int t = threadIdx.x;
  const int lane = t & 63, w = t >> 6;
  const int p = lane & 15, g = lane >> 4;
  const int bid = blockIdx.x;
  const int swz = (bid & 7) * 54 + (bid >> 3);   // bijective: 432 = 8 * 54
  const int l0 = (swz % 36) * 64, n = swz / 36;

  const unsigned short* Khead = Kb + (size_t)n * LTOK * HDIM;
  const unsigned short* Vhead = Vb + (size_t)n * (LTOK / 8) * 64 * 8;

  // ---- stage Q into padded Q_s (overlays P) ----
  {
    const int r = t >> 2, c = t & 3;
    const unsigned short* src = Qb + ((size_t)n * LTOK + l0 + r) * HDIM + c * 16;
    uint4 v0 = *(const uint4*)src;
    uint4 v1 = *(const uint4*)(src + 8);
    *(uint4*)&Q_s[r * 72 + c * 16] = v0;
    *(uint4*)&Q_s[r * 72 + c * 16 + 8] = v1;
  }
  __syncthreads();

  // ---- staging geometry ----
  const int rowb = lane >> 3;
  const int srcc = (lane & 7) ^ rowb;
  const int kc0 = w, kc1 = w + 4, kc2 = w + 8;   // this wave's chunks (of 12)

  // issue tile-0 stage into buffer 0 (latency hides under bias compute)
  {
    gld_lds16(K_lds + kc0 * 512, Khead + (size_t)(kc0 * 8 + rowb) * HDIM + srcc * 8);
    gld_lds16(K_lds + kc1 * 512, Khead + (size_t)(kc1 * 8 + rowb) * HDIM + srcc * 8);
    gld_lds16(K_lds + kc2 * 512, Khead + (size_t)(kc2 * 8 + rowb) * HDIM + srcc * 8);
    gld_lds16(V_lds + kc0 * 512, Vhead + kc0 * 512 + lane * 8);
    gld_lds16(V_lds + kc1 * 512, Vhead + kc1 * 512 + lane * 8);
    gld_lds16(V_lds + kc2 * 512, Vhead + kc2 * 512 + lane * 8);
  }
  // zero V pad keychunks 12,13 of BOTH buffers
  if (t < 128) *(uint4*)&V_lds[6144 + t * 8] = uint4{0u, 0u, 0u, 0u};
  else         *(uint4*)&V_lds[7168 + 6144 + (t - 128) * 8] = uint4{0u, 0u, 0u, 0u};

  const s16x8 qf0 = *(const s16x8*)&Q_s[(w * 16 + p) * 72 + g * 8];
  const s16x8 qf1 = *(const s16x8*)&Q_s[(w * 16 + p) * 72 + 32 + g * 8];

  const int qh_lane = (l0 + lane) / 48;
#pragma unroll
  for (int i = 0; i < 12; ++i) {
    const int kh = w + 4 * i;
    const float* rrow = relh + (size_t)(qh_lane - kh + 47) * HDIM;
    float acc = 0.f;
#pragma unroll
    for (int c8 = 0; c8 < 8; ++c8) {
      s16x8 qv = *(const s16x8*)&Q_s[lane * 72 + c8 * 8];
      float4 ra = *(const float4*)&rrow[c8 * 8];
      float4 rb = *(const float4*)&rrow[c8 * 8 + 4];
      acc += b2f((unsigned short)qv[0]) * ra.x + b2f((unsigned short)qv[1]) * ra.y +
             b2f((unsigned short)qv[2]) * ra.z + b2f((unsigned short)qv[3]) * ra.w +
             b2f((unsigned short)qv[4]) * rb.x + b2f((unsigned short)qv[5]) * rb.y +
             b2f((unsigned short)qv[6]) * rb.z + b2f((unsigned short)qv[7]) * rb.w;
    }
    bh_t[kh * 64 + lane] = acc * 8.0f;   // undo Q prescale
  }

  float bwreg[12];
  {
    const int qrow = w * 16 + p;
    const int qw_lane = (l0 + qrow) % 48;
#pragma unroll
    for (int mb = 0; mb < 3; ++mb)
#pragma unroll
      for (int jj = 0; jj < 4; ++jj) {
        const int j = 16 * mb + 4 * g + jj;
        const float* rrow = relw + (size_t)(qw_lane - j + 47) * HDIM;
        float acc = 0.f;
#pragma unroll
        for (int c8 = 0; c8 < 8; ++c8) {
          s16x8 qv = *(const s16x8*)&Q_s[qrow * 72 + c8 * 8];
          float4 ra = *(const float4*)&rrow[c8 * 8];
          float4 rb = *(const float4*)&rrow[c8 * 8 + 4];
          acc += b2f((unsigned short)qv[0]) * ra.x + b2f((unsigned short)qv[1]) * ra.y +
                 b2f((unsigned short)qv[2]) * ra.z + b2f((unsigned short)qv[3]) * ra.w +
                 b2f((unsigned short)qv[4]) * rb.x + b2f((unsigned short)qv[5]) * rb.y +
                 b2f((unsigned short)qv[6]) * rb.z + b2f((unsigned short)qv[7]) * rb.w;
        }
        bwreg[mb * 4 + jj] = acc * 8.0f;
      }
  }
  __syncthreads();  // Q dead; tile-0 loads drained; V pads visible

  // P zero pads (keys [48,64) per row)
  {
    uint2 z = {0u, 0u};
    *(uint2*)&P_lds[(w * 16 + p) * 72 + 48 + 4 * g] = z;
  }

  float lsum = 0.f;
  f32x4 accO[4] = {};
  const int sw0 = g ^ (p & 7);
  const int sw1 = (g + 4) ^ (p & 7);
  unsigned short* const Pw = P_lds + w * 16 * 72;

#pragma unroll 1
  for (int kt = 0; kt < 24; ++kt) {
    const int ko = (kt & 1) * 6144;
    const int vo = (kt & 1) * 7168;
    if (kt < 23) {
      const int nko = 6144 - ko, nvo = 7168 - vo;
      const int kb = (kt + 1) * 96;
      const int vb = (kt + 1) * 12;
      gld_lds16(K_lds + nko + kc0 * 512, Khead + (size_t)(kb + kc0 * 8 + rowb) * HDIM + srcc * 8);
      gld_lds16(K_lds + nko + kc1 * 512, Khead + (size_t)(kb + kc1 * 8 + rowb) * HDIM + srcc * 8);
      gld_lds16(K_lds + nko + kc2 * 512, Khead + (size_t)(kb + kc2 * 8 + rowb) * HDIM + srcc * 8);
      gld_lds16(V_lds + nvo + kc0 * 512, Vhead + (vb + kc0) * 512 + lane * 8);
      gld_lds16(V_lds + nvo + kc1 * 512, Vhead + (vb + kc1) * 512 + lane * 8);
      gld_lds16(V_lds + nvo + kc2 * 512, Vhead + (vb + kc2) * 512 + lane * 8);
    }

#pragma unroll 1
    for (int h = 0; h < 2; ++h) {
      f32x4 st[3] = {};
      __builtin_amdgcn_s_setprio(1);
#pragma unroll
      for (int mb = 0; mb < 3; ++mb) {
        const int krow = ko + (h * 48 + 16 * mb + p) * 64;
        s16x8 kf0 = *(const s16x8*)&K_lds[krow + sw0 * 8];
        s16x8 kf1 = *(const s16x8*)&K_lds[krow + sw1 * 8];
        st[mb] = __builtin_amdgcn_mfma_f32_16x16x32_bf16(kf0, qf0, st[mb], 0, 0, 0);
        st[mb] = __builtin_amdgcn_mfma_f32_16x16x32_bf16(kf1, qf1, st[mb], 0, 0, 0);
      }
      __builtin_amdgcn_s_setprio(0);

      const float bhv = bh_t[(2 * kt + h) * 64 + w * 16 + p] - 8.0f;
      float pv[12], ps = 0.f;
#pragma unroll
      for (int mb = 0; mb < 3; ++mb)
#pragma unroll
        for (int jj = 0; jj < 4; ++jj) {
          const float sv = st[mb][jj] + bhv + bwreg[mb * 4 + jj];
          pv[mb * 4 + jj] = __expf(sv);
          ps += pv[mb * 4 + jj];
        }
      lsum += ps;

#pragma unroll
      for (int mb = 0; mb < 3; ++mb) {
        unsigned int lo = (unsigned int)f2b(pv[mb * 4 + 0]) | ((unsigned int)f2b(pv[mb * 4 + 1]) << 16);
        unsigned int hi = (unsigned int)f2b(pv[mb * 4 + 2]) | ((unsigned int)f2b(pv[mb * 4 + 3]) << 16);
        uint2 val = {lo, hi};
        *(uint2*)&Pw[p * 72 + 16 * mb + 4 * g] = val;
      }

      const s16x8 pf0 = *(const s16x8*)&Pw[p * 72 + g * 8];
      const s16x8 pf1 = *(const s16x8*)&Pw[p * 72 + 32 + g * 8];
      __builtin_amdgcn_s_setprio(1);
#pragma unroll
      for (int db = 0; db < 4; ++db) {
        const int drow = 16 * db + p;
        s16x8 vf0 = *(const s16x8*)&V_lds[vo + ((6 * h + g) * 64 + drow) * 8];
        s16x8 vf1 = *(const s16x8*)&V_lds[vo + ((6 * h + 4 + g) * 64 + drow) * 8];
        accO[db] = __builtin_amdgcn_mfma_f32_16x16x32_bf16(vf0, pf0, accO[db], 0, 0, 0);
        accO[db] = __builtin_amdgcn_mfma_f32_16x16x32_bf16(vf1, pf1, accO[db], 0, 0, 0);
      }
      __builtin_amdgcn_s_setprio(0);
    }

    __syncthreads();
  }

  // epilogue
  float ls = lsum + __shfl_xor(lsum, 16, 64);
  ls += __shfl_xor(ls, 32, 64);
  const float inv = 1.0f / ls;
  unsigned short* orow = out + (size_t)(l0 + w * 16 + p) * CDIM + n * HDIM;
#pragma unroll
  for (int db = 0; db < 4; ++db) {
    unsigned int lo = (unsigned int)f2b(accO[db][0] * inv) | ((unsigned int)f2b(accO[db][1] * inv) << 16);
    unsigned int hi = (unsigned int)f2b(accO[db][2] * inv) | ((unsigned int)f2b(accO[db][3] * inv) << 16);
    uint2 val = {lo, hi};
    *(uint2*)&orow[16 * db + 4 * g] = val;
  }
}

// ---------------- launch ----------------
extern "C" void kernel_launch(void* const* d_in, const int* in_sizes, int n_in,
                              void* d_out, int out_size, void* d_ws, size_t ws_size,
                              hipStream_t stream) {
  const float* x     = (const float*)d_in[0];
  const float* ln1w  = (const float*)d_in[1];
  const float* ln1b  = (const float*)d_in[2];
  const float* qkvw  = (const float*)d_in[3];
  const float* qkvb  = (const float*)d_in[4];
  const float* relh  = (const float*)d_in[5];
  const float* relw  = (const float*)d_in[6];
  const float* projw = (const float*)d_in[7];
  const float* projb = (const float*)d_in[8];
  const float* ln2w  = (const float*)d_in[9];
  const float* ln2b  = (const float*)d_in[10];
  const float* fc1w  = (const float*)d_in[11];
  const float* fc1b  = (const float*)d_in[12];
  const float* fc2w  = (const float*)d_in[13];
  const float* fc2b  = (const float*)d_in[14];
  float* out = (float*)d_out;
  float* ws = (float*)d_ws;

  float* qkv = ws;                             // L*3C f32
  float* x1  = qkv + (size_t)LTOK * 3 * CDIM;  // L*C f32 (overlaid by Qb/Kb before proj)
  float* cs  = x1 + (size_t)LTOK * CDIM;
  float* sn  = cs + (size_t)LTOK * 32;
  unsigned short* h_bf    = (unsigned short*)(sn + (size_t)LTOK * 32);
  unsigned short* attn_bf = h_bf + (size_t)LTOK * CDIM;
  unsigned short* wq      = attn_bf + (size_t)LTOK * CDIM;
  unsigned short* wproj   = wq + (size_t)3 * CDIM * CDIM;
  unsigned short* wfc1    = wproj + (size_t)CDIM * CDIM;
  unsigned short* wfc2    = wfc1 + (size_t)4 * CDIM * CDIM;
  unsigned short* Qb      = (unsigned short*)x1;   // Qb+Kb fit x1 exactly
  unsigned short* Kb      = Qb + (size_t)NHEAD * LTOK * HDIM;
  unsigned short* Vb      = wq;                    // overlay: wq dead after qkv GEMM
  unsigned short* m1_bf   = (unsigned short*)qkv;  // overlay: qkv dead after prep

  // weight conversions (single fused launch)
  f2b4_kernel<<<3456, 256, 0, stream>>>(qkvw, projw, fc1w, fc2w, wq, wproj, wfc1, wfc2);

  ln_kernel<<<LTOK, 256, 0, stream>>>(x, ln1w, ln1b, h_bf);
  gemm64<false, false, false><<<dim3(18, 36), 256, 0, stream>>>(
      h_bf, wq, qkvb, nullptr, qkv, LTOK, 3 * CDIM, CDIM);
  rope_cs_kernel<<<288, 256, 0, stream>>>(cs, sn);
  prep_kernel<<<dim3(36, 12), 256, 0, stream>>>(qkv, cs, sn, Qb, Kb, Vb);
  attn_mfma<<<432, 256, 0, stream>>>(Qb, Kb, Vb, relh, relw, attn_bf);
  gemm64<false, true, false><<<dim3(6, 36), 256, 0, stream>>>(
      attn_bf, wproj, projb, x, x1, LTOK, CDIM, CDIM);
  ln_kernel<<<LTOK, 256, 0, stream>>>(x1, ln2w, ln2b, h_bf);
  gemm64<true, false, true><<<dim3(24, 36), 256, 0, stream>>>(
      h_bf, wfc1, fc1b, nullptr, m1_bf, LTOK, 4 * CDIM, CDIM);
  gemm64<false, true, false><<<dim3(6, 36), 256, 0, stream>>>(
      m1_bf, wfc2, fc2b, x1, out, LTOK, CDIM, 4 * CDIM);
}